// Round 5
// baseline (323.749 us; speedup 1.0000x reference)
//
#include <hip/hip_runtime.h>

#define Mm 160000
#define Nn 10000

typedef __attribute__((ext_vector_type(8))) short short8;
typedef __attribute__((ext_vector_type(4))) float float4v;

__device__ __forceinline__ short f2bf(float f) {
  // round-to-nearest-even fp32 -> bf16 (inputs are finite, no NaN handling)
  unsigned u = __builtin_bit_cast(unsigned, f);
  u = (u + 0x7FFFu + ((u >> 16) & 1u)) >> 16;
  return (short)u;
}

// pack two fp32 -> one u32 of two bf16 (RNE), low = a, high = b
__device__ __forceinline__ unsigned f2bf2(float a, float b) {
  unsigned ua = __builtin_bit_cast(unsigned, a);
  unsigned ub = __builtin_bit_cast(unsigned, b);
  ua = (ua + 0x7FFFu + ((ua >> 16) & 1u)) >> 16;
  ub = (ub + 0x7FFFu + ((ub >> 16) & 1u));
  return (ua & 0xFFFFu) | (ub & 0xFFFF0000u);
}

__device__ __forceinline__ short8 cvt8(float4 a, float4 b) {
  union { unsigned u[4]; short8 s; } r;
  r.u[0] = f2bf2(a.x, a.y);
  r.u[1] = f2bf2(a.z, a.w);
  r.u[2] = f2bf2(b.x, b.y);
  r.u[3] = f2bf2(b.z, b.w);
  return r.s;
}

__device__ __forceinline__ void gload_lds16(const void* g, void* l) {
  __builtin_amdgcn_global_load_lds(
      (const __attribute__((address_space(1))) unsigned*)g,
      (__attribute__((address_space(3))) unsigned*)l, 16, 0, 0);
}

// Wv [k=256][n=256] fp32 -> bt [n][k] bf16, PRE-SWIZZLED per 64-k slice:
// bt[n][a*64 + g*8 + e] = bf16(Wv[a*64 + (g^(n&7))*8 + e][n]).
// gemm_ln stages bt linearly into LDS via global_load_lds; the linear copy
// reproduces the verified 0-conflict XOR layout (linear dest + inverse-
// swizzled source + XOR on read).
__global__ __launch_bounds__(256) void prep_k(const float* __restrict__ Wv,
                                              short* __restrict__ bt) {
  const int n = blockIdx.x, k = threadIdx.x;
  const int ksrc = (k & 0xC7) | ((((k >> 3) ^ n) & 7) << 3);
  bt[n * 256 + k] = f2bf(Wv[ksrc * 256 + n]);
}

// Zero-barrier streaming GEMM+LN.
// Block = 512 thr (8 waves) x 128 rows; whole B (256x256 bf16 = 128 KB) in
// LDS, staged ONCE per block via global_load_lds -> single vmcnt(0)+s_barrier,
// then no barriers at all. Wave w owns rows m0+16w..+15, all 256 cols:
// A fragments load STRAIGHT from x (lane l&15 = row, l>>4 = k-quarter; two
// float4 per chunk — the exact MFMA A layout), ALL 16 loads issued up front so
// the wave streams HBM with 16 outstanding loads and never re-stalls.
// Per-head LayerNorm over col-frags 4h..4h+3 in-wave; scatter to final layout.
__global__ __launch_bounds__(512, 2) void gemm_ln(const float* __restrict__ x,
                                                  const short* __restrict__ bt,
                                                  const float* __restrict__ gamma,
                                                  const float* __restrict__ beta,
                                                  float* __restrict__ out) {
  __shared__ short Bt[256][256];  // 128 KB, swizzled content
  const int t = threadIdx.x;
  const int w = t >> 6;   // wave: rows m0+16w..m0+16w+15
  const int l = t & 63;
  const int c16 = l & 15;
  const int q = l >> 4;
  const int xk = c16 & 7;  // frag-read xor key (Bt row = j*16+c16, 16==0 mod 8)
  const int m0 = blockIdx.x * 128;
  const int row = m0 + w * 16 + c16;

  // 1) issue the wave's ENTIRE A stream: 16 float4 (this lane's 256B of row)
  float4 xa[8][2];
  const float* xp = x + (size_t)row * 256 + q * 8;
#pragma unroll
  for (int cc = 0; cc < 8; ++cc) {
    xa[cc][0] = *(const float4*)(xp + cc * 32);
    xa[cc][1] = *(const float4*)(xp + cc * 32 + 4);
  }

  // 2) stage whole B: 16 rounds x 512 thr x 16B = 128 KB (linear, async)
#pragma unroll
  for (int r = 0; r < 16; ++r)
    gload_lds16(bt + (size_t)r * 4096 + t * 8,
                (char*)&Bt[0][0] + r * 8192 + w * 1024);

  // single drain + barrier for the whole block
  asm volatile("s_waitcnt vmcnt(0)\n\ts_barrier" ::: "memory");

  // 3) main loop: 8 K-chunks, zero barriers
  float4v acc[16];
#pragma unroll
  for (int j = 0; j < 16; ++j) acc[j] = (float4v){0.f, 0.f, 0.f, 0.f};

#pragma unroll
  for (int cc = 0; cc < 8; ++cc) {
    const int a = cc >> 1, b = cc & 1;
    const short8 af = cvt8(xa[cc][0], xa[cc][1]);
    const int gi = a * 8 + (((b << 2) + q) ^ xk);  // swizzled 16B granule
#pragma unroll
    for (int j = 0; j < 16; ++j) {
      const short8 bf = *(const short8*)&Bt[j * 16 + c16][gi * 8];
      acc[j] = __builtin_amdgcn_mfma_f32_16x16x32_bf16(af, bf, acc[j], 0, 0, 0);
    }
  }

  // 4) epilogue: per-head LayerNorm + scatter.
  // C/D layout: col = c16 (within 16-tile), row = q*4 + reg.
  float gm[4], bb[4];
#pragma unroll
  for (int jj = 0; jj < 4; ++jj) {
    gm[jj] = gamma[jj * 16 + c16];
    bb[jj] = beta[jj * 16 + c16];
  }
  const int q4 = q * 4;
#pragma unroll
  for (int h = 0; h < 4; ++h) {
#pragma unroll
    for (int reg = 0; reg < 4; ++reg) {
      float s1 = acc[4 * h + 0][reg] + acc[4 * h + 1][reg] +
                 acc[4 * h + 2][reg] + acc[4 * h + 3][reg];
      float s2 = acc[4 * h + 0][reg] * acc[4 * h + 0][reg] +
                 acc[4 * h + 1][reg] * acc[4 * h + 1][reg] +
                 acc[4 * h + 2][reg] * acc[4 * h + 2][reg] +
                 acc[4 * h + 3][reg] * acc[4 * h + 3][reg];
      s1 += __shfl_xor(s1, 1); s2 += __shfl_xor(s2, 1);
      s1 += __shfl_xor(s1, 2); s2 += __shfl_xor(s2, 2);
      s1 += __shfl_xor(s1, 4); s2 += __shfl_xor(s2, 4);
      s1 += __shfl_xor(s1, 8); s2 += __shfl_xor(s2, 8);
      const float mu = s1 * (1.f / 64.f);
      const float var = s2 * (1.f / 64.f) - mu * mu;
      const float inv = rsqrtf(var + 1e-5f);
      const int m = m0 + w * 16 + q4 + reg;
      const int b = m / Nn;
      const int n = m - b * Nn;
      const size_t obase = (size_t)(n & 15) * 2560000u +
                           (size_t)(b * 625 + (n >> 4)) * 256u + h * 64 + c16;
#pragma unroll
      for (int jj = 0; jj < 4; ++jj)
        out[obase + jj * 16] =
            (acc[4 * h + jj][reg] - mu) * inv * gm[jj] + bb[jj];
    }
  }
}

extern "C" void kernel_launch(void* const* d_in, const int* in_sizes, int n_in,
                              void* d_out, int out_size, void* d_ws, size_t ws_size,
                              hipStream_t stream) {
  const float* x = (const float*)d_in[0];
  const float* Wv = (const float*)d_in[4];
  const float* gamma = (const float*)d_in[5];
  const float* beta = (const float*)d_in[6];
  float* out = (float*)d_out;
  short* wv_bt = (short*)d_ws;  // 256*256 bf16 = 128 KB

  prep_k<<<256, 256, 0, stream>>>(Wv, wv_bt);
  gemm_ln<<<Mm / 128, 512, 0, stream>>>(x, wv_bt, gamma, beta, out);
}

// Round 7
// 305.407 us; speedup vs baseline: 1.0601x; 1.0601x over previous
//
#include <hip/hip_runtime.h>

#define Nn 10000
#define TPR 10000   // output rows per residue (m/16 range)
#define GBLK 157    // ceil(TPR/64) g-blocks per residue; grid = 16*157

typedef __attribute__((ext_vector_type(8))) short short8;
typedef __attribute__((ext_vector_type(4))) short short4v;
typedef __attribute__((ext_vector_type(4))) float float4v;

__device__ __forceinline__ short f2bf(float f) {
  // round-to-nearest-even fp32 -> bf16 (inputs are finite, no NaN handling)
  unsigned u = __builtin_bit_cast(unsigned, f);
  u = (u + 0x7FFFu + ((u >> 16) & 1u)) >> 16;
  return (short)u;
}

// Wv [k=256][n=256] fp32 -> Wv_bt [n][k] bf16 (tiny, one-shot)
__global__ __launch_bounds__(256) void prep_k(const float* __restrict__ Wv,
                                              short* __restrict__ bt) {
  const int n = blockIdx.x, k = threadIdx.x;
  bt[n * 256 + k] = f2bf(Wv[k * 256 + n]);
}

// R0 structure (best measured: 100 us) with ONE change: block->row remapping
// for write locality. Block (r = blockIdx&15, g = blockIdx>>4) handles rows
// m = r + 16*(64g+s), s=0..63 (same residue mod 16). Output address is
// (m%16)*10.24MB + (m/16)*1KB + col*4, so the block's entire 64 KB of output
// is ONE contiguous window instead of 64B segments sprayed across 16 regions
// 10.24 MB apart. x reads become 1KB rows strided 16KB (still full cache
// lines, each read exactly once). Everything else identical to R0.
__global__ __launch_bounds__(256) void gemm_ln(const float* __restrict__ x,
                                               const short* __restrict__ bt,
                                               const float* __restrict__ gamma,
                                               const float* __restrict__ beta,
                                               float* __restrict__ out) {
  __shared__ short A[64][72];    // [s][k], +8 pad: stride 144B -> 2-way max
  __shared__ short Bt[256][72];  // [n][k]
  const int t = threadIdx.x;
  const int r16 = blockIdx.x & 15;        // output region = m % 16
  const int t0 = (blockIdx.x >> 4) * 64;  // base of m/16 for this block
  const int w = t >> 6;   // wave = head
  const int l = t & 63;
  const int c16 = l & 15;
  const int q8 = (l >> 4) * 8;

  float4v acc[4][4];
#pragma unroll
  for (int i = 0; i < 4; ++i)
#pragma unroll
    for (int j = 0; j < 4; ++j) acc[i][j] = (float4v){0.f, 0.f, 0.f, 0.f};

  const int ar = t >> 4, ak = (t & 15) * 4;   // A staging: 16 lanes cover a row
  const int bn = t >> 3, bk = (t & 7) * 8;    // B staging: 8 lanes cover a row

  for (int k0 = 0; k0 < 256; k0 += 64) {
    __syncthreads();
    // stage A: 64 rows x 64 k, fp32 global -> bf16 LDS (x read exactly once)
#pragma unroll
    for (int j = 0; j < 4; ++j) {
      int ts = t0 + ar + j * 16;
      if (ts > TPR - 1) ts = TPR - 1;  // tail clamp (g=156): safe re-read
      const size_t m = (size_t)r16 + 16u * (size_t)ts;
      float4 a = *(const float4*)(x + m * 256 + k0 + ak);
      short4v s;
      s.x = f2bf(a.x); s.y = f2bf(a.y); s.z = f2bf(a.z); s.w = f2bf(a.w);
      *(short4v*)&A[ar + j * 16][ak] = s;
    }
    // stage Bt: 256 n-rows x 64 k bf16 (L2-resident, 16B loads)
#pragma unroll
    for (int j = 0; j < 8; ++j) {
      int4 v = *(const int4*)(bt + (size_t)(bn + j * 32) * 256 + k0 + bk);
      *(int4*)&Bt[bn + j * 32][bk] = v;
    }
    __syncthreads();
#pragma unroll
    for (int c = 0; c < 2; ++c) {  // two K=32 chunks
      short8 af[4], bf[4];
#pragma unroll
      for (int i = 0; i < 4; ++i)
        af[i] = *(const short8*)&A[i * 16 + c16][c * 32 + q8];
#pragma unroll
      for (int j = 0; j < 4; ++j)
        bf[j] = *(const short8*)&Bt[w * 64 + j * 16 + c16][c * 32 + q8];
#pragma unroll
      for (int i = 0; i < 4; ++i)
#pragma unroll
        for (int j = 0; j < 4; ++j)
          acc[i][j] = __builtin_amdgcn_mfma_f32_16x16x32_bf16(af[i], bf[j],
                                                              acc[i][j], 0, 0, 0);
    }
  }

  // Epilogue: per-head LayerNorm + store into the block's contiguous window.
  // C/D layout: col = l&15 (within 16-tile), row = (l>>4)*4 + reg.
  float g[4], be[4];
#pragma unroll
  for (int j = 0; j < 4; ++j) {
    g[j] = gamma[j * 16 + c16];
    be[j] = beta[j * 16 + c16];
  }
  const int q4 = (l >> 4) * 4;
#pragma unroll
  for (int i = 0; i < 4; ++i) {
#pragma unroll
    for (int reg = 0; reg < 4; ++reg) {
      float s1 = acc[i][0][reg] + acc[i][1][reg] + acc[i][2][reg] + acc[i][3][reg];
      float s2 = acc[i][0][reg] * acc[i][0][reg] + acc[i][1][reg] * acc[i][1][reg] +
                 acc[i][2][reg] * acc[i][2][reg] + acc[i][3][reg] * acc[i][3][reg];
      s1 += __shfl_xor(s1, 1); s2 += __shfl_xor(s2, 1);
      s1 += __shfl_xor(s1, 2); s2 += __shfl_xor(s2, 2);
      s1 += __shfl_xor(s1, 4); s2 += __shfl_xor(s2, 4);
      s1 += __shfl_xor(s1, 8); s2 += __shfl_xor(s2, 8);
      const float mu = s1 * (1.f / 64.f);
      const float var = s2 * (1.f / 64.f) - mu * mu;
      const float inv = rsqrtf(var + 1e-5f);
      const int tOut = t0 + i * 16 + q4 + reg;
      if (tOut < TPR) {
        const size_t obase = (size_t)r16 * 2560000u + (size_t)tOut * 256u +
                             w * 64 + c16;
#pragma unroll
        for (int j = 0; j < 4; ++j)
          out[obase + j * 16] = (acc[i][j][reg] - mu) * inv * g[j] + be[j];
      }
    }
  }
}

extern "C" void kernel_launch(void* const* d_in, const int* in_sizes, int n_in,
                              void* d_out, int out_size, void* d_ws, size_t ws_size,
                              hipStream_t stream) {
  const float* x = (const float*)d_in[0];
  const float* Wv = (const float*)d_in[4];
  const float* gamma = (const float*)d_in[5];
  const float* beta = (const float*)d_in[6];
  float* out = (float*)d_out;
  short* wv_bt = (short*)d_ws;  // 256*256 bf16 = 128 KB

  prep_k<<<256, 256, 0, stream>>>(Wv, wv_bt);
  gemm_ln<<<16 * GBLK, 256, 0, stream>>>(x, wv_bt, gamma, beta, out);
}